// Round 1
// baseline (611.315 us; speedup 1.0000x reference)
//
#include <hip/hip_runtime.h>
#include <hip/hip_fp16.h>

#define NN 3072
#define DD 256
#define NH 8
#define BM 16
#define BN 64

typedef _Float16 h16;
typedef __attribute__((ext_vector_type(8))) _Float16 half8;
typedef __attribute__((ext_vector_type(4))) float f32x4;

// ---------------------------------------------------------------- convert ----
// xb = fp16(x); wt* = fp16(W^T) so MFMA B-frags read contiguous K.
__global__ __launch_bounds__(256) void k_convert(
    const float* __restrict__ x, const float* __restrict__ Wq,
    const float* __restrict__ Wk, const float* __restrict__ Wv,
    const float* __restrict__ Wo, h16* __restrict__ xb, h16* __restrict__ wtq,
    h16* __restrict__ wtk, h16* __restrict__ wtv, h16* __restrict__ wto) {
  int t = blockIdx.x * 256 + threadIdx.x;
  const int NX = NN * DD;
  if (t < NX) { xb[t] = (h16)x[t]; return; }
  int u = t - NX;
  int m = u >> 16;
  int e = u & 65535;
  int n = e >> 8, k = e & 255;
  const float* W = (m == 0) ? Wq : (m == 1) ? Wk : (m == 2) ? Wv : Wo;
  h16* wt = (m == 0) ? wtq : (m == 1) ? wtk : (m == 2) ? wtv : wto;
  wt[e] = (h16)W[(k << 8) + n];   // wt[n][k] = W[k][n]
}

// ---------------------------------------------------------------- prep dy ----
// dy_eff = valid ? dy (+ 2.5e-5 on diag, matching SELF_DISTANCE^2*0.25) : 3e4
__global__ __launch_bounds__(256) void k_prep(
    const float* __restrict__ dy, const int* __restrict__ dm,
    const int* __restrict__ bim, h16* __restrict__ dyeff) {
  int row = blockIdx.y;
  int col = blockIdx.x * 256 + threadIdx.x;
  size_t idx = (size_t)row * NN + col;
  bool diag = (row == col);
  bool valid = (dm[idx] != 0 && bim[idx] != 0) || diag;
  float v = valid ? (dy[idx] + (diag ? 2.5e-5f : 0.f)) : 30000.f;
  dyeff[idx] = (h16)v;
}

// ------------------------------------------------------------------- gemm ----
// C[M x 256] = A[M x 256] @ W + bias. Bt is W^T (row n holds K contiguous).
// mode 0: fp16 row-major, *scale   (q with 1/sqrt(32), k)
// mode 1: fp16 transposed (vt[n*M+m])  (v for the PV B-operand)
// mode 2: fp32 row-major + resid   (final out projection)
__global__ __launch_bounds__(256) void k_gemm(
    const h16* __restrict__ A, const h16* __restrict__ Bt,
    const float* __restrict__ bias, void* __restrict__ out,
    const float* __restrict__ resid, int M, int mode, float scale) {
  int lane = threadIdx.x & 63;
  int wave = threadIdx.x >> 6;
  int col = lane & 15, quad = lane >> 4;
  int m0 = blockIdx.x * 64;
  int n0 = blockIdx.y * 64 + wave * 16;
  f32x4 acc[4];
  #pragma unroll
  for (int i = 0; i < 4; ++i) acc[i] = (f32x4){0.f, 0.f, 0.f, 0.f};
  #pragma unroll
  for (int kk = 0; kk < DD; kk += 32) {
    half8 b = *(const half8*)(Bt + (size_t)(n0 + col) * DD + kk + quad * 8);
    #pragma unroll
    for (int mr = 0; mr < 4; ++mr) {
      half8 a = *(const half8*)(A + (size_t)(m0 + mr * 16 + col) * DD + kk + quad * 8);
      acc[mr] = __builtin_amdgcn_mfma_f32_16x16x32_f16(a, b, acc[mr], 0, 0, 0);
    }
  }
  float bb = bias[n0 + col];
  #pragma unroll
  for (int mr = 0; mr < 4; ++mr) {
    #pragma unroll
    for (int r = 0; r < 4; ++r) {
      int m = m0 + mr * 16 + quad * 4 + r;
      int n = n0 + col;
      float v = acc[mr][r] + bb;
      if (mode == 0)      ((h16*)out)[(size_t)m * DD + n] = (h16)(v * scale);
      else if (mode == 1) ((h16*)out)[(size_t)n * M + m] = (h16)v;
      else ((float*)out)[(size_t)m * DD + n] = v + resid[(size_t)m * DD + n];
    }
  }
}

// ------------------------------------------------------------- mean shift ----
// One iteration. Block = 16 queries x 8 waves (1 head/wave). Keys tiled by 64.
// logit = S + (-0.25(|xq|^2+|xk|^2) + 0.5 xq.xk) - dy_eff ; p = exp(logit)
// den/xyz accumulated per lane (cols), butterfly-reduced at the end.
// last iter: unnormalized P -> LDS (fp16) -> MFMA with vt for feat.
__global__ __launch_bounds__(512) void k_msattn(
    const h16* __restrict__ qb, const h16* __restrict__ kb,
    const h16* __restrict__ vt, const h16* __restrict__ dyeff,
    const float* __restrict__ xyz_in, float* __restrict__ xyz_out,
    h16* __restrict__ featb, int last) {
  __shared__ h16 s_dy[BM][BN + 2];        // +2 pad: break 128B-stride bank alias
  __shared__ float s_xyzk[BN * 3];
  __shared__ float s_xyzo[BM * 3];
  __shared__ h16 s_p[NH][BM][BN + 8];     // +8 pad: A-frag b128 reads 2-way max

  const int tid = threadIdx.x;
  const int h = tid >> 6;                 // wave == head
  const int lane = tid & 63;
  const int col = lane & 15;
  const int quad = lane >> 4;
  const int q0 = blockIdx.x * BM;

  if (tid < BM * 3) s_xyzo[tid] = 0.f;

  // fixed per-wave A-frag: q rows q0..q0+15, head h, K = Dh = 32 (one MFMA)
  half8 qfrag = *(const half8*)(qb + (size_t)(q0 + col) * DD + h * 32 + quad * 8);

  float xq[4][3], bq[4];
  #pragma unroll
  for (int r = 0; r < 4; ++r) {
    int qi = q0 + quad * 4 + r;
    xq[r][0] = xyz_in[qi * 3 + 0];
    xq[r][1] = xyz_in[qi * 3 + 1];
    xq[r][2] = xyz_in[qi * 3 + 2];
    bq[r] = -0.25f * (xq[r][0] * xq[r][0] + xq[r][1] * xq[r][1] + xq[r][2] * xq[r][2]);
  }

  float den[4] = {0.f, 0.f, 0.f, 0.f};
  float axz[4][3];
  #pragma unroll
  for (int r = 0; r < 4; ++r) axz[r][0] = axz[r][1] = axz[r][2] = 0.f;
  f32x4 fc0 = (f32x4){0.f, 0.f, 0.f, 0.f};
  f32x4 fc1 = (f32x4){0.f, 0.f, 0.f, 0.f};

  for (int kt = 0; kt < NN / BN; ++kt) {
    const int k0 = kt * BN;
    __syncthreads();
    {  // stage dy tile (16x64 halfs) + key xyz, coalesced
      int r = tid >> 5, c2 = tid & 31;
      *(unsigned int*)&s_dy[r][c2 * 2] =
          *(const unsigned int*)(dyeff + (size_t)(q0 + r) * NN + k0 + c2 * 2);
    }
    if (tid < BN * 3) s_xyzk[tid] = xyz_in[k0 * 3 + tid];
    __syncthreads();

    #pragma unroll
    for (int f = 0; f < 4; ++f) {
      int kloc = f * 16 + col;
      half8 kf = *(const half8*)(kb + (size_t)(k0 + kloc) * DD + h * 32 + quad * 8);
      f32x4 s = __builtin_amdgcn_mfma_f32_16x16x32_f16(
          qfrag, kf, (f32x4){0.f, 0.f, 0.f, 0.f}, 0, 0, 0);
      float kx = s_xyzk[kloc * 3 + 0];
      float ky = s_xyzk[kloc * 3 + 1];
      float kz = s_xyzk[kloc * 3 + 2];
      float nk2 = kx * kx + ky * ky + kz * kz;
      #pragma unroll
      for (int r = 0; r < 4; ++r) {
        float dot = xq[r][0] * kx + xq[r][1] * ky + xq[r][2] * kz;
        float t = fmaf(nk2, -0.25f, bq[r]);
        t = fmaf(dot, 0.5f, t);
        float logit = s[r] + t - (float)s_dy[quad * 4 + r][kloc];
        float p = __expf(logit);   // no max-subtraction: logits are O(1), safe
        den[r] += p;
        axz[r][0] = fmaf(p, kx, axz[r][0]);
        axz[r][1] = fmaf(p, ky, axz[r][1]);
        axz[r][2] = fmaf(p, kz, axz[r][2]);
        if (last) s_p[h][quad * 4 + r][kloc] = (h16)p;
      }
    }
    if (last) {  // PV: P tile (own wave's LDS region, no barrier needed)
      #pragma unroll
      for (int c = 0; c < 2; ++c) {
        half8 pf = *(const half8*)&s_p[h][col][c * 32 + quad * 8];
        half8 v0 = *(const half8*)(vt + (size_t)(h * 32 + col) * NN + k0 + c * 32 + quad * 8);
        half8 v1 = *(const half8*)(vt + (size_t)(h * 32 + 16 + col) * NN + k0 + c * 32 + quad * 8);
        fc0 = __builtin_amdgcn_mfma_f32_16x16x32_f16(pf, v0, fc0, 0, 0, 0);
        fc1 = __builtin_amdgcn_mfma_f32_16x16x32_f16(pf, v1, fc1, 0, 0, 0);
      }
    }
  }

  // butterfly reduce over the 16 cols (quads share identical rows)
  #pragma unroll
  for (int m = 1; m < 16; m <<= 1) {
    #pragma unroll
    for (int r = 0; r < 4; ++r) {
      den[r] += __shfl_xor(den[r], m);
      axz[r][0] += __shfl_xor(axz[r][0], m);
      axz[r][1] += __shfl_xor(axz[r][1], m);
      axz[r][2] += __shfl_xor(axz[r][2], m);
    }
  }
  if (last) {
    #pragma unroll
    for (int r = 0; r < 4; ++r) {
      float inv = 1.f / den[r];
      size_t o = (size_t)(q0 + quad * 4 + r) * DD + h * 32;
      featb[o + col] = (h16)(fc0[r] * inv);
      featb[o + 16 + col] = (h16)(fc1[r] * inv);
    }
  }
  if (col == 0) {  // per-head xyz contribution: mean over heads of attn@xyz
    #pragma unroll
    for (int r = 0; r < 4; ++r) {
      float inv = 1.f / (8.f * den[r]);
      int q = quad * 4 + r;
      atomicAdd(&s_xyzo[q * 3 + 0], axz[r][0] * inv);
      atomicAdd(&s_xyzo[q * 3 + 1], axz[r][1] * inv);
      atomicAdd(&s_xyzo[q * 3 + 2], axz[r][2] * inv);
    }
  }
  __syncthreads();
  if (tid < BM * 3) xyz_out[q0 * 3 + tid] = s_xyzo[tid];
}

// ----------------------------------------------------------------- launch ----
extern "C" void kernel_launch(void* const* d_in, const int* in_sizes, int n_in,
                              void* d_out, int out_size, void* d_ws, size_t ws_size,
                              hipStream_t stream) {
  const float* x   = (const float*)d_in[0];
  const float* xyz = (const float*)d_in[1];
  const float* dy  = (const float*)d_in[2];
  const int* dm    = (const int*)d_in[3];
  const int* bim   = (const int*)d_in[4];
  const float* Wq = (const float*)d_in[5];
  const float* bq = (const float*)d_in[6];
  const float* Wk = (const float*)d_in[7];
  const float* bk = (const float*)d_in[8];
  const float* Wv = (const float*)d_in[9];
  const float* bv = (const float*)d_in[10];
  const float* Wo = (const float*)d_in[11];
  const float* bo = (const float*)d_in[12];

  char* p = (char*)d_ws;
  h16* xb  = (h16*)p; p += (size_t)NN * DD * 2;
  h16* wtq = (h16*)p; p += 256 * 256 * 2;
  h16* wtk = (h16*)p; p += 256 * 256 * 2;
  h16* wtv = (h16*)p; p += 256 * 256 * 2;
  h16* wto = (h16*)p; p += 256 * 256 * 2;
  h16* qb    = (h16*)p; p += (size_t)NN * DD * 2;
  h16* kb    = (h16*)p; p += (size_t)NN * DD * 2;
  h16* vt    = (h16*)p; p += (size_t)NN * DD * 2;
  h16* featb = (h16*)p; p += (size_t)NN * DD * 2;
  h16* dyeff = (h16*)p; p += (size_t)NN * NN * 2;
  float* xyzA = (float*)p; p += (size_t)NN * 3 * 4;
  float* xyzB = (float*)p; p += (size_t)NN * 3 * 4;

  k_convert<<<4096, 256, 0, stream>>>(x, Wq, Wk, Wv, Wo, xb, wtq, wtk, wtv, wto);
  k_prep<<<dim3(12, NN), 256, 0, stream>>>(dy, dm, bim, dyeff);
  // fold 1/sqrt(Dh) into q
  k_gemm<<<dim3(48, 4), 256, 0, stream>>>(xb, wtq, bq, qb, nullptr, NN, 0, 0.17677669529663689f);
  k_gemm<<<dim3(48, 4), 256, 0, stream>>>(xb, wtk, bk, kb, nullptr, NN, 0, 1.f);
  k_gemm<<<dim3(48, 4), 256, 0, stream>>>(xb, wtv, bv, vt, nullptr, NN, 1, 1.f);

  float* xyz_final = (float*)d_out;            // output 0: [3072,3]
  float* out_final = (float*)d_out + NN * 3;   // output 1: [3072,256]
  k_msattn<<<NN / BM, 512, 0, stream>>>(qb, kb, vt, dyeff, xyz,  xyzA, nullptr, 0);
  k_msattn<<<NN / BM, 512, 0, stream>>>(qb, kb, vt, dyeff, xyzA, xyzB, nullptr, 0);
  k_msattn<<<NN / BM, 512, 0, stream>>>(qb, kb, vt, dyeff, xyzB, xyz_final, featb, 1);
  k_gemm<<<dim3(48, 4), 256, 0, stream>>>(featb, wto, bo, out_final, x, NN, 2, 1.f);
}

// Round 2
// 560.310 us; speedup vs baseline: 1.0910x; 1.0910x over previous
//
#include <hip/hip_runtime.h>
#include <hip/hip_fp16.h>

#define NN 3072
#define DD 256
#define NH 8
#define SPLIT 4
#define KT (NN / SPLIT / 64)   // 12 key-tiles of 64 per split

typedef _Float16 h16;
typedef __attribute__((ext_vector_type(4))) _Float16 half4;
typedef __attribute__((ext_vector_type(8))) _Float16 half8;
typedef __attribute__((ext_vector_type(4))) float f32x4;

// ---------------------------------------------------------------- convert ----
__global__ __launch_bounds__(256) void k_convert(
    const float* __restrict__ x, const float* __restrict__ Wq,
    const float* __restrict__ Wk, const float* __restrict__ Wv,
    const float* __restrict__ Wo, h16* __restrict__ xb, h16* __restrict__ wtq,
    h16* __restrict__ wtk, h16* __restrict__ wtv, h16* __restrict__ wto) {
  int t = blockIdx.x * 256 + threadIdx.x;
  const int NX = NN * DD;
  if (t < NX) { xb[t] = (h16)x[t]; return; }
  int u = t - NX;
  int m = u >> 16;
  int e = u & 65535;
  int n = e >> 8, k = e & 255;
  const float* W = (m == 0) ? Wq : (m == 1) ? Wk : (m == 2) ? Wv : Wo;
  h16* wt = (m == 0) ? wtq : (m == 1) ? wtk : (m == 2) ? wtv : wto;
  wt[e] = (h16)W[(k << 8) + n];   // wt[n][k] = W[k][n]
}

// ---------------------------------------------------------------- prep dy ----
// dy_eff = valid ? dy (+2.5e-5 on diag = BETA*inv2bw2*SELF_DISTANCE^2) : 3e4
__global__ __launch_bounds__(256) void k_prep(
    const float* __restrict__ dy, const int* __restrict__ dm,
    const int* __restrict__ bim, h16* __restrict__ dyeff) {
  int row = blockIdx.y;
  int col = blockIdx.x * 256 + threadIdx.x;
  size_t idx = (size_t)row * NN + col;
  bool diag = (row == col);
  bool valid = (dm[idx] != 0 && bim[idx] != 0) || diag;
  float v = valid ? (dy[idx] + (diag ? 2.5e-5f : 0.f)) : 30000.f;
  dyeff[idx] = (h16)v;
}

// ------------------------------------------------------------------- gemm ----
// mode 0: fp16 row-major *scale; mode 1: fp16 transposed [n*M+m]; mode 2: fp32 +resid
__global__ __launch_bounds__(256) void k_gemm(
    const h16* __restrict__ A, const h16* __restrict__ Bt,
    const float* __restrict__ bias, void* __restrict__ out,
    const float* __restrict__ resid, int M, int mode, float scale) {
  int lane = threadIdx.x & 63;
  int wave = threadIdx.x >> 6;
  int col = lane & 15, quad = lane >> 4;
  int m0 = blockIdx.x * 32;
  int n0 = blockIdx.y * 64 + wave * 16;
  f32x4 acc[2];
  acc[0] = (f32x4){0.f, 0.f, 0.f, 0.f};
  acc[1] = (f32x4){0.f, 0.f, 0.f, 0.f};
  #pragma unroll
  for (int kk = 0; kk < DD; kk += 32) {
    half8 b = *(const half8*)(Bt + (size_t)(n0 + col) * DD + kk + quad * 8);
    #pragma unroll
    for (int mr = 0; mr < 2; ++mr) {
      half8 a = *(const half8*)(A + (size_t)(m0 + mr * 16 + col) * DD + kk + quad * 8);
      acc[mr] = __builtin_amdgcn_mfma_f32_16x16x32_f16(a, b, acc[mr], 0, 0, 0);
    }
  }
  float bb = bias[n0 + col];
  #pragma unroll
  for (int mr = 0; mr < 2; ++mr) {
    #pragma unroll
    for (int r = 0; r < 4; ++r) {
      int m = m0 + mr * 16 + quad * 4 + r;
      int n = n0 + col;
      float v = acc[mr][r] + bb;
      if (mode == 0)      ((h16*)out)[(size_t)m * DD + n] = (h16)(v * scale);
      else if (mode == 1) ((h16*)out)[(size_t)n * M + m] = (h16)v;
      else ((float*)out)[(size_t)m * DD + n] = v + resid[(size_t)m * DD + n];
    }
  }
}

// --------------------------------------------------------------- xyz4 init ---
__global__ __launch_bounds__(256) void k_xyz4(const float* __restrict__ xyz,
                                              float4* __restrict__ xyz4) {
  int q = blockIdx.x * 256 + threadIdx.x;
  if (q >= NN) return;
  float x = xyz[q * 3], y = xyz[q * 3 + 1], z = xyz[q * 3 + 2];
  xyz4[q] = make_float4(x, y, z, -0.25f * (x * x + y * y + z * z));
}

// ------------------------------------------------------------- mean shift ----
// Block: 16 queries x 8 waves (wave = head), key range = split of 768 keys.
// Orientation: A = K rows, B = Q rows -> D[key = quad*4+r][query = col].
// C preloaded with -dy (contiguous b64 per lane). No LDS / barriers except
// the last-iter P round-trip (per-wave region, no barrier needed).
template <int LAST>
__global__ __launch_bounds__(512) void k_msattn(
    const h16* __restrict__ qb, const h16* __restrict__ kb,
    const h16* __restrict__ vt, const h16* __restrict__ dyeff,
    const float4* __restrict__ xyz4, float* __restrict__ den_g,
    float* __restrict__ axz_g, float* __restrict__ numT) {
  __shared__ h16 s_p[LAST ? NH : 1][16][72];   // 72: 16B-aligned rows, 2-way banks
  const int tid = threadIdx.x;
  const int h = tid >> 6;
  const int lane = tid & 63;
  const int col = lane & 15;
  const int quad = lane >> 4;
  const int q0 = blockIdx.x * 16;
  const int kbase = blockIdx.y * (NN / SPLIT);

  half8 qf = *(const half8*)(qb + (size_t)(q0 + col) * DD + h * 32 + quad * 8);
  float4 xq = xyz4[q0 + col];      // w = -0.25*|xq|^2
  float den = 0.f, ax = 0.f, ay = 0.f, az = 0.f;
  f32x4 fc0 = (f32x4){0.f, 0.f, 0.f, 0.f};
  f32x4 fc1 = (f32x4){0.f, 0.f, 0.f, 0.f};

  for (int kt = 0; kt < KT; ++kt) {
    const int k0 = kbase + kt * 64;
    #pragma unroll
    for (int f = 0; f < 4; ++f) {
      const int kf0 = k0 + f * 16;
      half4 dy4 = *(const half4*)(dyeff + (size_t)(q0 + col) * NN + kf0 + quad * 4);
      f32x4 cc;
      cc[0] = -(float)dy4[0];
      cc[1] = -(float)dy4[1];
      cc[2] = -(float)dy4[2];
      cc[3] = -(float)dy4[3];
      half8 kf = *(const half8*)(kb + (size_t)(kf0 + col) * DD + h * 32 + quad * 8);
      f32x4 s = __builtin_amdgcn_mfma_f32_16x16x32_f16(kf, qf, cc, 0, 0, 0);
      half4 pv;
      #pragma unroll
      for (int r = 0; r < 4; ++r) {
        float4 xk = xyz4[kf0 + quad * 4 + r];          // broadcast across 16 lanes
        float dot = fmaf(xq.x, xk.x, fmaf(xq.y, xk.y, xq.z * xk.z));
        float logit = fmaf(dot, 0.5f, s[r] + (xq.w + xk.w));
        float p = __expf(logit);                       // logits O(1); no max needed
        den += p;
        ax = fmaf(p, xk.x, ax);
        ay = fmaf(p, xk.y, ay);
        az = fmaf(p, xk.z, az);
        if (LAST) pv[r] = (h16)p;
      }
      if (LAST) *(half4*)&s_p[h][col][f * 16 + quad * 4] = pv;
    }
    if (LAST) {  // PV: feat^T partial via MFMA (A = vt rows, B = P columns)
      #pragma unroll
      for (int c = 0; c < 2; ++c) {
        half8 pf = *(const half8*)&s_p[h][col][c * 32 + quad * 8];
        half8 v0 = *(const half8*)(vt + (size_t)(h * 32 + col) * NN + k0 + c * 32 + quad * 8);
        half8 v1 = *(const half8*)(vt + (size_t)(h * 32 + 16 + col) * NN + k0 + c * 32 + quad * 8);
        fc0 = __builtin_amdgcn_mfma_f32_16x16x32_f16(v0, pf, fc0, 0, 0, 0);
        fc1 = __builtin_amdgcn_mfma_f32_16x16x32_f16(v1, pf, fc1, 0, 0, 0);
      }
    }
  }

  // reduce across the 4 quads (lane bits 4,5)
  #pragma unroll
  for (int m = 16; m <= 32; m <<= 1) {
    den += __shfl_xor(den, m);
    ax += __shfl_xor(ax, m);
    ay += __shfl_xor(ay, m);
    az += __shfl_xor(az, m);
  }
  if (quad == 0) {
    int q = q0 + col;
    atomicAdd(&den_g[h * NN + q], den);
    atomicAdd(&axz_g[(h * NN + q) * 3 + 0], ax);
    atomicAdd(&axz_g[(h * NN + q) * 3 + 1], ay);
    atomicAdd(&axz_g[(h * NN + q) * 3 + 2], az);
  }
  if (LAST) {
    #pragma unroll
    for (int r = 0; r < 4; ++r) {
      atomicAdd(&numT[(size_t)(h * 32 + quad * 4 + r) * NN + q0 + col], fc0[r]);
      atomicAdd(&numT[(size_t)(h * 32 + 16 + quad * 4 + r) * NN + q0 + col], fc1[r]);
    }
  }
}

// ---------------------------------------------------------------- combine ----
// xyz_new[q] = (1/8) sum_h axz[h][q]/den[h][q]; writes float4 (w=-0.25|x|^2)
// for the next iteration, or raw [N,3] floats for the final output.
__global__ __launch_bounds__(256) void k_combine(
    const float* __restrict__ den_g, const float* __restrict__ axz_g,
    float4* __restrict__ xyz4, float* __restrict__ out3) {
  int q = blockIdx.x * 256 + threadIdx.x;
  if (q >= NN) return;
  float x = 0.f, y = 0.f, z = 0.f;
  #pragma unroll
  for (int h = 0; h < NH; ++h) {
    float inv = 0.125f / den_g[h * NN + q];
    x = fmaf(axz_g[(h * NN + q) * 3 + 0], inv, x);
    y = fmaf(axz_g[(h * NN + q) * 3 + 1], inv, y);
    z = fmaf(axz_g[(h * NN + q) * 3 + 2], inv, z);
  }
  if (out3) {
    out3[q * 3 + 0] = x;
    out3[q * 3 + 1] = y;
    out3[q * 3 + 2] = z;
  } else {
    xyz4[q] = make_float4(x, y, z, -0.25f * (x * x + y * y + z * z));
  }
}

// ----------------------------------------------------------------- finish ----
// featb[q][d] = numT[d][q] / den[d/32][q]   (32x32 LDS transpose tiles)
__global__ __launch_bounds__(256) void k_finish(
    const float* __restrict__ numT, const float* __restrict__ den_g,
    h16* __restrict__ featb) {
  __shared__ float tile[32][33];
  int q0 = blockIdx.x * 32, d0 = blockIdx.y * 32;
  int tx = threadIdx.x & 31, ty = threadIdx.x >> 5;   // 32 x 8
  #pragma unroll
  for (int i = 0; i < 4; ++i)
    tile[ty + i * 8][tx] = numT[(size_t)(d0 + ty + i * 8) * NN + q0 + tx];
  __syncthreads();
  int h = d0 >> 5;
  #pragma unroll
  for (int i = 0; i < 4; ++i) {
    int q = q0 + ty + i * 8;
    float inv = 1.f / den_g[h * NN + q];
    featb[(size_t)q * DD + d0 + tx] = (h16)(tile[tx][ty + i * 8] * inv);
  }
}

// ----------------------------------------------------------------- launch ----
extern "C" void kernel_launch(void* const* d_in, const int* in_sizes, int n_in,
                              void* d_out, int out_size, void* d_ws, size_t ws_size,
                              hipStream_t stream) {
  const float* x   = (const float*)d_in[0];
  const float* xyz = (const float*)d_in[1];
  const float* dy  = (const float*)d_in[2];
  const int* dm    = (const int*)d_in[3];
  const int* bim   = (const int*)d_in[4];
  const float* Wq = (const float*)d_in[5];
  const float* bq = (const float*)d_in[6];
  const float* Wk = (const float*)d_in[7];
  const float* bk = (const float*)d_in[8];
  const float* Wv = (const float*)d_in[9];
  const float* bv = (const float*)d_in[10];
  const float* Wo = (const float*)d_in[11];
  const float* bo = (const float*)d_in[12];

  char* p = (char*)d_ws;
  h16* xb  = (h16*)p; p += (size_t)NN * DD * 2;
  h16* wtq = (h16*)p; p += 256 * 256 * 2;
  h16* wtk = (h16*)p; p += 256 * 256 * 2;
  h16* wtv = (h16*)p; p += 256 * 256 * 2;
  h16* wto = (h16*)p; p += 256 * 256 * 2;
  h16* qb    = (h16*)p; p += (size_t)NN * DD * 2;
  h16* kb    = (h16*)p; p += (size_t)NN * DD * 2;
  h16* vt    = (h16*)p; p += (size_t)NN * DD * 2;
  h16* featb = (h16*)p; p += (size_t)NN * DD * 2;
  h16* dyeff = (h16*)p; p += (size_t)NN * NN * 2;
  // accumulator region (zeroed once per launch)
  char* accbase = p;
  float* den_i[3];
  float* axz_i[3];
  for (int i = 0; i < 3; ++i) { den_i[i] = (float*)p; p += NH * NN * 4; }
  for (int i = 0; i < 3; ++i) { axz_i[i] = (float*)p; p += NH * NN * 3 * 4; }
  float* numT = (float*)p; p += (size_t)DD * NN * 4;
  size_t accbytes = (size_t)(p - accbase);
  float4* xyz4_0 = (float4*)p; p += NN * 16;
  float4* xyz4_1 = (float4*)p; p += NN * 16;
  float4* xyz4_2 = (float4*)p; p += NN * 16;

  hipMemsetAsync(accbase, 0, accbytes, stream);
  k_convert<<<4096, 256, 0, stream>>>(x, Wq, Wk, Wv, Wo, xb, wtq, wtk, wtv, wto);
  k_prep<<<dim3(12, NN), 256, 0, stream>>>(dy, dm, bim, dyeff);
  k_gemm<<<dim3(96, 4), 256, 0, stream>>>(xb, wtq, bq, qb, nullptr, NN, 0, 0.17677669529663689f);
  k_gemm<<<dim3(96, 4), 256, 0, stream>>>(xb, wtk, bk, kb, nullptr, NN, 0, 1.f);
  k_gemm<<<dim3(96, 4), 256, 0, stream>>>(xb, wtv, bv, vt, nullptr, NN, 1, 1.f);
  k_xyz4<<<12, 256, 0, stream>>>(xyz, xyz4_0);

  float* xyz_final = (float*)d_out;            // output 0: [3072,3]
  float* out_final = (float*)d_out + NN * 3;   // output 1: [3072,256]

  k_msattn<0><<<dim3(NN / 16, SPLIT), 512, 0, stream>>>(
      qb, kb, vt, dyeff, xyz4_0, den_i[0], axz_i[0], nullptr);
  k_combine<<<12, 256, 0, stream>>>(den_i[0], axz_i[0], xyz4_1, nullptr);
  k_msattn<0><<<dim3(NN / 16, SPLIT), 512, 0, stream>>>(
      qb, kb, vt, dyeff, xyz4_1, den_i[1], axz_i[1], nullptr);
  k_combine<<<12, 256, 0, stream>>>(den_i[1], axz_i[1], xyz4_2, nullptr);
  k_msattn<1><<<dim3(NN / 16, SPLIT), 512, 0, stream>>>(
      qb, kb, vt, dyeff, xyz4_2, den_i[2], axz_i[2], numT);
  k_combine<<<12, 256, 0, stream>>>(den_i[2], axz_i[2], nullptr, xyz_final);
  k_finish<<<dim3(96, 8), 256, 0, stream>>>(numT, den_i[2], featb);
  k_gemm<<<dim3(96, 4), 256, 0, stream>>>(featb, wto, bo, out_final, x, NN, 2, 1.f);
}

// Round 3
// 478.887 us; speedup vs baseline: 1.2765x; 1.1700x over previous
//
#include <hip/hip_runtime.h>
#include <hip/hip_fp16.h>

#define NN 3072
#define DD 256
#define NH 8
#define SPLIT 4
#define KT (NN / SPLIT / 64)   // 12 key-tiles of 64 per split
#define LN2INV 1.4426950408889634f

typedef _Float16 h16;
typedef __attribute__((ext_vector_type(4))) _Float16 half4;
typedef __attribute__((ext_vector_type(8))) _Float16 half8;
typedef __attribute__((ext_vector_type(4))) float f32x4;

#if __has_builtin(__builtin_amdgcn_exp2f)
#define EXP2(x) __builtin_amdgcn_exp2f(x)
#else
#define EXP2(x) __expf((x) * 0.69314718056f)
#endif

// ---------------------------------------------------------------- convert ----
__global__ __launch_bounds__(256) void k_convert(
    const float* __restrict__ x, const float* __restrict__ Wq,
    const float* __restrict__ Wk, const float* __restrict__ Wv,
    const float* __restrict__ Wo, h16* __restrict__ xb, h16* __restrict__ wtq,
    h16* __restrict__ wtk, h16* __restrict__ wtv, h16* __restrict__ wto) {
  int t = blockIdx.x * 256 + threadIdx.x;
  const int NX = NN * DD;
  if (t < NX) { xb[t] = (h16)x[t]; return; }
  int u = t - NX;
  int m = u >> 16;
  int e = u & 65535;
  int n = e >> 8, k = e & 255;
  const float* W = (m == 0) ? Wq : (m == 1) ? Wk : (m == 2) ? Wv : Wo;
  h16* wt = (m == 0) ? wtq : (m == 1) ? wtk : (m == 2) ? wtv : wto;
  wt[e] = (h16)W[(k << 8) + n];   // wt[n][k] = W[k][n]
}

// ---------------------------------------------------------------- prep dy ----
// dyn = valid ? -LN2INV*(dy + diag*2.5e-5) : -43281 (base-2 logit units)
__global__ __launch_bounds__(256) void k_prep(
    const float* __restrict__ dy, const int* __restrict__ dm,
    const int* __restrict__ bim, h16* __restrict__ dyn) {
  int row = blockIdx.y;
  int col = blockIdx.x * 256 + threadIdx.x;
  size_t idx = (size_t)row * NN + col;
  bool diag = (row == col);
  bool valid = (dm[idx] != 0 && bim[idx] != 0) || diag;
  float v = valid ? (-LN2INV * (dy[idx] + (diag ? 2.5e-5f : 0.f))) : -43281.f;
  dyn[idx] = (h16)v;
}

// ------------------------------------------------------------------- gemm ----
__global__ __launch_bounds__(256) void k_gemm(
    const h16* __restrict__ A, const h16* __restrict__ Bt,
    const float* __restrict__ bias, void* __restrict__ out,
    const float* __restrict__ resid, int M, int mode, float scale) {
  int lane = threadIdx.x & 63;
  int wave = threadIdx.x >> 6;
  int col = lane & 15, quad = lane >> 4;
  int m0 = blockIdx.x * 32;
  int n0 = blockIdx.y * 64 + wave * 16;
  f32x4 acc[2];
  acc[0] = (f32x4){0.f, 0.f, 0.f, 0.f};
  acc[1] = (f32x4){0.f, 0.f, 0.f, 0.f};
  #pragma unroll
  for (int kk = 0; kk < DD; kk += 32) {
    half8 b = *(const half8*)(Bt + (size_t)(n0 + col) * DD + kk + quad * 8);
    #pragma unroll
    for (int mr = 0; mr < 2; ++mr) {
      half8 a = *(const half8*)(A + (size_t)(m0 + mr * 16 + col) * DD + kk + quad * 8);
      acc[mr] = __builtin_amdgcn_mfma_f32_16x16x32_f16(a, b, acc[mr], 0, 0, 0);
    }
  }
  float bb = bias[n0 + col];
  #pragma unroll
  for (int mr = 0; mr < 2; ++mr) {
    #pragma unroll
    for (int r = 0; r < 4; ++r) {
      int m = m0 + mr * 16 + quad * 4 + r;
      int n = n0 + col;
      float v = acc[mr][r] + bb;
      if (mode == 0)      ((h16*)out)[(size_t)m * DD + n] = (h16)(v * scale);
      else if (mode == 1) ((h16*)out)[(size_t)n * M + m] = (h16)v;
      else ((float*)out)[(size_t)m * DD + n] = v + resid[(size_t)m * DD + n];
    }
  }
}

// ------------------------------------------------------------- aug writer ----
// qaug[q][32]: B-operand dims; kaug[k][32]: A-operand dims; xyzT[16][NN]:
// Sum-p MFMA A rows {1, xh,yh,zh, xl,yl,zl, 0...}.
__device__ inline void write_aug(int q, float x, float y, float z,
                                 h16* __restrict__ qaug, h16* __restrict__ kaug,
                                 h16* __restrict__ xyzT) {
  float sx = 0.5f * LN2INV * x, sy = 0.5f * LN2INV * y, sz = 0.5f * LN2INV * z;
  h16 shx = (h16)sx, shy = (h16)sy, shz = (h16)sz;
  h16 slx = (h16)(sx - (float)shx), sly = (h16)(sy - (float)shy), slz = (h16)(sz - (float)shz);
  h16 hx = (h16)x, hy = (h16)y, hz = (h16)z;
  h16 lx = (h16)(x - (float)hx), ly = (h16)(y - (float)hy), lz = (h16)(z - (float)hz);
  float n2n = -0.25f * LN2INV * (x * x + y * y + z * z);
  h16 nh = (h16)n2n, nl = (h16)(n2n - (float)nh);
  h16 qa[32], ka[32];
  #pragma unroll
  for (int i = 0; i < 32; ++i) { qa[i] = (h16)0.f; ka[i] = (h16)0.f; }
  // geo = (shq+slq).(hk+lk) + (nh_k+nl_k) + n2n_q  [all in log2 units]
  qa[0] = shx; qa[1] = shy; qa[2] = shz;       // pairs A d0-2 = hk
  qa[3] = shx; qa[4] = shy; qa[5] = shz;       // pairs A d3-5 = lk
  qa[6] = slx; qa[7] = sly; qa[8] = slz;       // pairs A d6-8 = hk
  qa[9] = (h16)1.f; qa[10] = (h16)1.f;         // pairs key-norm hi/lo
  qa[11] = (h16)n2n;                           // query norm (row-const)
  ka[0] = hx; ka[1] = hy; ka[2] = hz;
  ka[3] = lx; ka[4] = ly; ka[5] = lz;
  ka[6] = hx; ka[7] = hy; ka[8] = hz;
  ka[9] = nh; ka[10] = nl;
  ka[11] = (h16)1.f;
  #pragma unroll
  for (int i = 0; i < 4; ++i) {
    ((half8*)(qaug + (size_t)q * 32))[i] = ((half8*)qa)[i];
    ((half8*)(kaug + (size_t)q * 32))[i] = ((half8*)ka)[i];
  }
  xyzT[q] = (h16)1.f;
  xyzT[1 * NN + q] = hx; xyzT[2 * NN + q] = hy; xyzT[3 * NN + q] = hz;
  xyzT[4 * NN + q] = lx; xyzT[5 * NN + q] = ly; xyzT[6 * NN + q] = lz;
  #pragma unroll
  for (int r = 7; r < 16; ++r) xyzT[(size_t)r * NN + q] = (h16)0.f;
}

__global__ __launch_bounds__(256) void k_aug0(const float* __restrict__ xyz,
                                              h16* __restrict__ qaug,
                                              h16* __restrict__ kaug,
                                              h16* __restrict__ xyzT) {
  int q = blockIdx.x * 256 + threadIdx.x;
  if (q >= NN) return;
  write_aug(q, xyz[q * 3], xyz[q * 3 + 1], xyz[q * 3 + 2], qaug, kaug, xyzT);
}

// ------------------------------------------------------------- mean shift ----
// Block: 16 queries x 8 waves (wave = head); 768-key split. Per f (16 keys):
//   geo-MFMA(kaug,qaug,C=-dy) -> content-MFMA(kf,qf,C=geo) -> exp2 -> p(fp16)
// Per kt (64 keys): Sum-p MFMA (A=xyzT: den + xyz numerator hi/lo), LAST: PV.
template <int LAST>
__global__ __launch_bounds__(512, 4) void k_msattn(
    const h16* __restrict__ qb, const h16* __restrict__ kb,
    const h16* __restrict__ vt, const h16* __restrict__ dyn,
    const h16* __restrict__ qaug, const h16* __restrict__ kaug,
    const h16* __restrict__ xyzT, float* __restrict__ den_s,
    float* __restrict__ axh_s, float* __restrict__ axl_s,
    float* __restrict__ numT) {
  __shared__ h16 s_dy[16][776];           // row 1552B: 16B-aligned, ~4-way read
  __shared__ h16 s_p[NH][16][72];         // per-wave region, no barrier needed
  const int tid = threadIdx.x;
  const int h = tid >> 6;
  const int lane = tid & 63;
  const int col = lane & 15;
  const int quad = lane >> 4;
  const int q0 = blockIdx.x * 16;
  const int kbase = blockIdx.y * (NN / SPLIT);

  {  // stage the block's dy rows (16 x 768 fp16) once
    int qr = tid >> 5, c = tid & 31;
    const h16* src = dyn + (size_t)(q0 + qr) * NN + kbase;
    #pragma unroll
    for (int pass = 0; pass < 3; ++pass) {
      int k = c * 8 + pass * 256;
      *(half8*)&s_dy[qr][k] = *(const half8*)(src + k);
    }
  }
  __syncthreads();

  half8 qf  = *(const half8*)(qb + (size_t)(q0 + col) * DD + h * 32 + quad * 8);
  half8 qaf = *(const half8*)(qaug + (size_t)(q0 + col) * 32 + quad * 8);
  f32x4 accS = (f32x4){0.f, 0.f, 0.f, 0.f};
  f32x4 fc0 = (f32x4){0.f, 0.f, 0.f, 0.f};
  f32x4 fc1 = (f32x4){0.f, 0.f, 0.f, 0.f};

  for (int kt = 0; kt < KT; ++kt) {
    const int k0 = kbase + kt * 64;
    #pragma unroll
    for (int f = 0; f < 4; ++f) {
      const int kf0 = k0 + f * 16;
      half4 dy4 = *(const half4*)&s_dy[col][kt * 64 + f * 16 + quad * 4];
      f32x4 cc;
      cc[0] = (float)dy4[0];
      cc[1] = (float)dy4[1];
      cc[2] = (float)dy4[2];
      cc[3] = (float)dy4[3];
      half8 kaf = *(const half8*)(kaug + (size_t)(kf0 + col) * 32 + quad * 8);
      f32x4 g = __builtin_amdgcn_mfma_f32_16x16x32_f16(kaf, qaf, cc, 0, 0, 0);
      half8 kf = *(const half8*)(kb + (size_t)(kf0 + col) * DD + h * 32 + quad * 8);
      f32x4 s = __builtin_amdgcn_mfma_f32_16x16x32_f16(kf, qf, g, 0, 0, 0);
      half4 pv;
      #pragma unroll
      for (int r = 0; r < 4; ++r) pv[r] = (h16)EXP2(s[r]);
      *(half4*)&s_p[h][col][f * 16 + quad * 4] = pv;
    }
    #pragma unroll
    for (int c = 0; c < 2; ++c) {
      half8 pf = *(const half8*)&s_p[h][col][c * 32 + quad * 8];
      half8 xf = *(const half8*)(xyzT + (size_t)col * NN + k0 + c * 32 + quad * 8);
      accS = __builtin_amdgcn_mfma_f32_16x16x32_f16(xf, pf, accS, 0, 0, 0);
      if (LAST) {
        half8 v0 = *(const half8*)(vt + (size_t)(h * 32 + col) * NN + k0 + c * 32 + quad * 8);
        half8 v1 = *(const half8*)(vt + (size_t)(h * 32 + 16 + col) * NN + k0 + c * 32 + quad * 8);
        fc0 = __builtin_amdgcn_mfma_f32_16x16x32_f16(v0, pf, fc0, 0, 0, 0);
        fc1 = __builtin_amdgcn_mfma_f32_16x16x32_f16(v1, pf, fc1, 0, 0, 0);
      }
    }
  }

  // accS D rows: 0=den, 1-3=num_hi, 4-6=num_lo (rows 7-15 zero)
  int q = q0 + col;
  size_t sidx = (size_t)(blockIdx.y * NH + h) * NN + q;
  if (quad == 0) {
    den_s[sidx] = accS[0];
    axh_s[sidx * 3 + 0] = accS[1];
    axh_s[sidx * 3 + 1] = accS[2];
    axh_s[sidx * 3 + 2] = accS[3];
  } else if (quad == 1) {
    axl_s[sidx * 3 + 0] = accS[0];
    axl_s[sidx * 3 + 1] = accS[1];
    axl_s[sidx * 3 + 2] = accS[2];
  }
  if (LAST) {
    #pragma unroll
    for (int r = 0; r < 4; ++r) {
      atomicAdd(&numT[(size_t)(h * 32 + quad * 4 + r) * NN + q], fc0[r]);
      atomicAdd(&numT[(size_t)(h * 32 + 16 + quad * 4 + r) * NN + q], fc1[r]);
    }
  }
}

// ---------------------------------------------------------------- combine ----
__global__ __launch_bounds__(256) void k_combine(
    const float* __restrict__ den_s, const float* __restrict__ axh_s,
    const float* __restrict__ axl_s, float* __restrict__ den_tot,
    h16* __restrict__ qaug, h16* __restrict__ kaug, h16* __restrict__ xyzT,
    float* __restrict__ out3) {
  int q = blockIdx.x * 256 + threadIdx.x;
  if (q >= NN) return;
  float X = 0.f, Y = 0.f, Z = 0.f;
  #pragma unroll
  for (int h = 0; h < NH; ++h) {
    float d = 0.f, x = 0.f, y = 0.f, z = 0.f;
    #pragma unroll
    for (int s = 0; s < SPLIT; ++s) {
      size_t idx = (size_t)(s * NH + h) * NN + q;
      d += den_s[idx];
      x += axh_s[idx * 3 + 0] + axl_s[idx * 3 + 0];
      y += axh_s[idx * 3 + 1] + axl_s[idx * 3 + 1];
      z += axh_s[idx * 3 + 2] + axl_s[idx * 3 + 2];
    }
    den_tot[h * NN + q] = d;
    float inv = 0.125f / d;
    X = fmaf(x, inv, X);
    Y = fmaf(y, inv, Y);
    Z = fmaf(z, inv, Z);
  }
  if (out3) {
    out3[q * 3 + 0] = X;
    out3[q * 3 + 1] = Y;
    out3[q * 3 + 2] = Z;
  } else {
    write_aug(q, X, Y, Z, qaug, kaug, xyzT);
  }
}

// ----------------------------------------------------------------- finish ----
__global__ __launch_bounds__(256) void k_finish(
    const float* __restrict__ numT, const float* __restrict__ den_tot,
    h16* __restrict__ featb) {
  __shared__ float tile[32][33];
  int q0 = blockIdx.x * 32, d0 = blockIdx.y * 32;
  int tx = threadIdx.x & 31, ty = threadIdx.x >> 5;   // 32 x 8
  #pragma unroll
  for (int i = 0; i < 4; ++i)
    tile[ty + i * 8][tx] = numT[(size_t)(d0 + ty + i * 8) * NN + q0 + tx];
  __syncthreads();
  int h = d0 >> 5;
  #pragma unroll
  for (int i = 0; i < 4; ++i) {
    int q = q0 + ty + i * 8;
    float inv = 1.f / den_tot[h * NN + q];
    featb[(size_t)q * DD + d0 + tx] = (h16)(tile[tx][ty + i * 8] * inv);
  }
}

// ----------------------------------------------------------------- launch ----
extern "C" void kernel_launch(void* const* d_in, const int* in_sizes, int n_in,
                              void* d_out, int out_size, void* d_ws, size_t ws_size,
                              hipStream_t stream) {
  const float* x   = (const float*)d_in[0];
  const float* xyz = (const float*)d_in[1];
  const float* dy  = (const float*)d_in[2];
  const int* dm    = (const int*)d_in[3];
  const int* bim   = (const int*)d_in[4];
  const float* Wq = (const float*)d_in[5];
  const float* bq = (const float*)d_in[6];
  const float* Wk = (const float*)d_in[7];
  const float* bk = (const float*)d_in[8];
  const float* Wv = (const float*)d_in[9];
  const float* bv = (const float*)d_in[10];
  const float* Wo = (const float*)d_in[11];
  const float* bo = (const float*)d_in[12];

  char* p = (char*)d_ws;
  h16* xb  = (h16*)p; p += (size_t)NN * DD * 2;
  h16* wtq = (h16*)p; p += 256 * 256 * 2;
  h16* wtk = (h16*)p; p += 256 * 256 * 2;
  h16* wtv = (h16*)p; p += 256 * 256 * 2;
  h16* wto = (h16*)p; p += 256 * 256 * 2;
  h16* qb    = (h16*)p; p += (size_t)NN * DD * 2;
  h16* kb    = (h16*)p; p += (size_t)NN * DD * 2;
  h16* vt    = (h16*)p; p += (size_t)NN * DD * 2;
  h16* featb = (h16*)p; p += (size_t)NN * DD * 2;
  h16* dyn   = (h16*)p; p += (size_t)NN * NN * 2;
  h16* qaug  = (h16*)p; p += (size_t)NN * 32 * 2;
  h16* kaug  = (h16*)p; p += (size_t)NN * 32 * 2;
  h16* xyzT  = (h16*)p; p += (size_t)16 * NN * 2;
  float* den_s = (float*)p; p += (size_t)SPLIT * NH * NN * 4;
  float* axh_s = (float*)p; p += (size_t)SPLIT * NH * NN * 3 * 4;
  float* axl_s = (float*)p; p += (size_t)SPLIT * NH * NN * 3 * 4;
  float* den_tot = (float*)p; p += (size_t)NH * NN * 4;
  float* numT = (float*)p; p += (size_t)DD * NN * 4;

  hipMemsetAsync(numT, 0, (size_t)DD * NN * 4, stream);
  k_convert<<<4096, 256, 0, stream>>>(x, Wq, Wk, Wv, Wo, xb, wtq, wtk, wtv, wto);
  k_prep<<<dim3(12, NN), 256, 0, stream>>>(dy, dm, bim, dyn);
  // fold 1/sqrt(Dh) and ln2^-1 into q
  k_gemm<<<dim3(96, 4), 256, 0, stream>>>(xb, wtq, bq, qb, nullptr, NN, 0,
                                          0.17677669529663689f * LN2INV);
  k_gemm<<<dim3(96, 4), 256, 0, stream>>>(xb, wtk, bk, kb, nullptr, NN, 0, 1.f);
  k_gemm<<<dim3(96, 4), 256, 0, stream>>>(xb, wtv, bv, vt, nullptr, NN, 1, 1.f);
  k_aug0<<<12, 256, 0, stream>>>(xyz, qaug, kaug, xyzT);

  float* xyz_final = (float*)d_out;            // output 0: [3072,3]
  float* out_final = (float*)d_out + NN * 3;   // output 1: [3072,256]

  k_msattn<0><<<dim3(NN / 16, SPLIT), 512, 0, stream>>>(
      qb, kb, vt, dyn, qaug, kaug, xyzT, den_s, axh_s, axl_s, nullptr);
  k_combine<<<12, 256, 0, stream>>>(den_s, axh_s, axl_s, den_tot,
                                    qaug, kaug, xyzT, nullptr);
  k_msattn<0><<<dim3(NN / 16, SPLIT), 512, 0, stream>>>(
      qb, kb, vt, dyn, qaug, kaug, xyzT, den_s, axh_s, axl_s, nullptr);
  k_combine<<<12, 256, 0, stream>>>(den_s, axh_s, axl_s, den_tot,
                                    qaug, kaug, xyzT, nullptr);
  k_msattn<1><<<dim3(NN / 16, SPLIT), 512, 0, stream>>>(
      qb, kb, vt, dyn, qaug, kaug, xyzT, den_s, axh_s, axl_s, numT);
  k_combine<<<12, 256, 0, stream>>>(den_s, axh_s, axl_s, den_tot,
                                    nullptr, nullptr, nullptr, xyz_final);
  k_finish<<<dim3(96, 8), 256, 0, stream>>>(numT, den_tot, featb);
  k_gemm<<<dim3(96, 4), 256, 0, stream>>>(featb, wto, bo, out_final, x, NN, 2, 1.f);
}